// Round 3
// baseline (1173.919 us; speedup 1.0000x reference)
//
#include <hip/hip_runtime.h>
#include <hip/hip_bf16.h>
#include <stdint.h>

#define N_TOK 8192
#define DIM 1024
#define HID 4096
#define NEXP 8
#define NSLOT 16384  // N_TOK * top_k
#define NBLK 64      // NSLOT / 256

typedef __attribute__((ext_vector_type(8))) __bf16 bf16x8;
typedef __attribute__((ext_vector_type(4))) float f32x4;

__device__ __forceinline__ unsigned short f2bf(float f) {
  unsigned int u = __float_as_uint(f);
  u += 0x7fff + ((u >> 16) & 1);  // round-to-nearest-even
  return (unsigned short)(u >> 16);
}
__device__ __forceinline__ float bf2f(unsigned short s) {
  return __uint_as_float(((unsigned int)s) << 16);
}
__device__ __forceinline__ void async16(const void* g, void* l) {
  __builtin_amdgcn_global_load_lds((__attribute__((address_space(1))) void*)(g),
                                   (__attribute__((address_space(3))) void*)(l), 16, 0, 0);
}
#define MFMA16(a, b, c) __builtin_amdgcn_mfma_f32_16x16x32_bf16(a, b, c, 0, 0, 0)

// ---------------- fp32 -> bf16 weight conversion ----------------
__global__ void cvt_kernel(const float* __restrict__ src, unsigned short* __restrict__ dst,
                           int n4) {
  int i = blockIdx.x * 256 + threadIdx.x;
  int stride = gridDim.x * 256;
  for (; i < n4; i += stride) {
    float4 v = ((const float4*)src)[i];
    ushort4 o;
    o.x = f2bf(v.x); o.y = f2bf(v.y); o.z = f2bf(v.z); o.w = f2bf(v.w);
    ((ushort4*)dst)[i] = o;
  }
}

// ---------------- gating: 1 wave per token (no global atomics) ----------------
__global__ void gate_kernel(const float* __restrict__ x, const float* __restrict__ gw,
                            const float* __restrict__ gb, int* __restrict__ expert2,
                            float* __restrict__ score2) {
  int token = blockIdx.x * 4 + (threadIdx.x >> 6);
  int lane = threadIdx.x & 63;
  const float4* xr = (const float4*)(x + (size_t)token * DIM);
  float acc[NEXP];
#pragma unroll
  for (int e = 0; e < NEXP; ++e) acc[e] = 0.f;
#pragma unroll
  for (int it = 0; it < DIM / 4 / 64; ++it) {
    int d = it * 64 + lane;
    float4 xv = xr[d];
#pragma unroll
    for (int e = 0; e < NEXP; ++e) {
      float4 wv = ((const float4*)(gw + e * DIM))[d];
      acc[e] += xv.x * wv.x + xv.y * wv.y + xv.z * wv.z + xv.w * wv.w;
    }
  }
#pragma unroll
  for (int off = 32; off > 0; off >>= 1) {
#pragma unroll
    for (int e = 0; e < NEXP; ++e) acc[e] += __shfl_xor(acc[e], off, 64);
  }
  if (lane == 0) {
    float lg[NEXP], mx = -1e30f;
#pragma unroll
    for (int e = 0; e < NEXP; ++e) { lg[e] = acc[e] + gb[e]; mx = fmaxf(mx, lg[e]); }
    float p[NEXP], s = 0.f;
#pragma unroll
    for (int e = 0; e < NEXP; ++e) { p[e] = expf(lg[e] - mx); s += p[e]; }
    float inv = 1.f / s;
#pragma unroll
    for (int e = 0; e < NEXP; ++e) p[e] *= inv;
    int i0 = 0;
#pragma unroll
    for (int e = 1; e < NEXP; ++e) if (p[e] > p[i0]) i0 = e;
    int i1 = (i0 == 0) ? 1 : 0;
#pragma unroll
    for (int e = 0; e < NEXP; ++e) if (e != i0 && p[e] > p[i1]) i1 = e;
    float eb = expf(p[i1] - p[i0]);  // <= 1
    float dn = 1.f / (1.f + eb);
    expert2[token * 2] = i0;
    expert2[token * 2 + 1] = i1;
    score2[token * 2] = dn;
    score2[token * 2 + 1] = eb * dn;
  }
}

// ---------------- routing: hist -> scan -> assign (LDS atomics only) ----------
__global__ void hist_kernel(const int* __restrict__ expert2, int* __restrict__ hist) {
  __shared__ int lh[NEXP];
  int b = blockIdx.x, t = threadIdx.x;
  if (t < NEXP) lh[t] = 0;
  __syncthreads();
  atomicAdd(&lh[expert2[b * 256 + t]], 1);
  __syncthreads();
  if (t < NEXP) hist[b * NEXP + t] = lh[t];
}

__global__ void scan_kernel(const int* __restrict__ hist, int* __restrict__ cnt,
                            int* __restrict__ off_, int* __restrict__ base) {
  __shared__ int lh[NBLK * NEXP];
  __shared__ int ltot[NEXP];
  __shared__ int loff[NEXP];
  int t = threadIdx.x;  // 64 threads
#pragma unroll
  for (int e = 0; e < NEXP; ++e) lh[t * NEXP + e] = hist[t * NEXP + e];
  __syncthreads();
  if (t < NEXP) {
    int s = 0;
    for (int b = 0; b < NBLK; ++b) { int v = lh[b * NEXP + t]; lh[b * NEXP + t] = s; s += v; }
    ltot[t] = s;
  }
  __syncthreads();
  if (t == 0) {
    int s = 0;
#pragma unroll
    for (int e = 0; e < NEXP; ++e) { loff[e] = s; s += ltot[e]; }
  }
  __syncthreads();
  if (t < NEXP) { cnt[t] = ltot[t]; off_[t] = loff[t]; }
#pragma unroll
  for (int e = 0; e < NEXP; ++e) base[t * NEXP + e] = loff[e] + lh[t * NEXP + e];
}

__global__ void assign_kernel(const int* __restrict__ expert2, const int* __restrict__ base,
                              int* __restrict__ slot_of, int* __restrict__ token_of) {
  __shared__ int lh[NEXP];
  int b = blockIdx.x, t = threadIdx.x;
  if (t < NEXP) lh[t] = 0;
  __syncthreads();
  int i = b * 256 + t;
  int e = expert2[i];
  int r = atomicAdd(&lh[e], 1);
  int slot = base[b * NEXP + e] + r;
  slot_of[i] = slot;
  token_of[slot] = i >> 1;
}

__global__ void gather_kernel(const float* __restrict__ x, const int* __restrict__ token_of,
                              unsigned short* __restrict__ xg) {
  int slot = blockIdx.x;
  int t = threadIdx.x;
  int n = token_of[slot];
  float4 v = *(const float4*)(x + (size_t)n * DIM + t * 4);
  ushort4 o;
  o.x = f2bf(v.x); o.y = f2bf(v.y); o.z = f2bf(v.z); o.w = f2bf(v.w);
  *(ushort4*)(xg + (size_t)slot * DIM + t * 4) = o;
}

// ===================== 256x256 8-phase bf16 MFMA GEMM =====================
// C[m][n] = sum_k A[m][k]*B[n][k] (+bias, opt relu), rows = expert slots.
// BM=BN=256, BK=64. 512 threads = 8 waves (2M x 4N), wave output 128x64,
// acc = 8x4 f32x4. LDS 128KB: 2 tile-buffers x (A 32KB + B 32KB), linear
// [256][64] bf16, chunk-XOR swizzle slot = kc^(row&7); pre-swizzled GLOBAL
// source + swizzled READ, linear gload_lds dest (rule #21; round-1 verified
// 0 bank conflicts).
// Schedule per K-tile t (buffer p = t&1), T3+T4+T5:
//   P1: ds_read aks0[0-3]+bks0 (8xb128) | stage (t+1,A1)->p^1 | bar;
//       lgkm(0); schedbar; prio1; 16 MFMA (ks0, mt0-3); prio0; bar
//   P2: ds_read aks0[4-7]+aks1[0-7]+bks1 (16xb128) | stage (t+1,B1)->p^1 |
//       bar; lgkm(0); schedbar  <- ALL buf-p reads complete before any wave
//       passes the P2-end barrier; prio1; 16 MFMA (ks0, mt4-7); prio0; bar
//   P3: stage (t+2,A0)->p (safe now) | bar; prio1; 16 MFMA (ks1,mt0-3); bar
//   P4: stage (t+2,B0)->p | bar; prio1; 16 MFMA (ks1,mt4-7); prio0;
//       vmcnt(4) (leaves exactly (t+2,A0/B0) in flight => tile t+1 resident;
//       never 0 in steady state); schedbar; bar
// Prologue: stage tile0 (4 halves) + tile1 A0,B0; vmcnt(4). Epilogue: P4 wait
// flips to vmcnt(0) when t+2>=NT (load-count trace verified).
// Round-3 hardening vs round-2 (container died, no counters): (a) register-
// lean reads (peak frag 80 VGPR, was 96) + 32-bit voffset addressing (~-12
// VGPR) -> ~230 < 256 cap; (b) #pragma unroll 2 bounds code size for NT=64.
template <int KLEN, int NLEN, bool RELU>
__global__ __launch_bounds__(512, 2) void gemm256(
    const unsigned short* __restrict__ A, const unsigned short* __restrict__ B,
    const float* __restrict__ bias, unsigned short* __restrict__ C,
    const int* __restrict__ cnt, const int* __restrict__ off_) {
  const int NB_N = NLEN / 256;
  const int NT = KLEN / 64;
  int panel = blockIdx.z * 8 + blockIdx.x;  // T1: panel pinned to XCD
  int e = panel / NB_N;
  int n0 = (panel % NB_N) * 256;
  int me = cnt[e];
  int m0 = blockIdx.y * 256;
  if (m0 >= me) return;
  int rb = off_[e] + m0;

  __shared__ unsigned short lA[2][16384];  // 2 x 32KB
  __shared__ unsigned short lB[2][16384];  // 2 x 32KB

  int tid = threadIdx.x;
  int wave = tid >> 6, lane = tid & 63;
  int wm = wave >> 2, wn = wave & 3;
  int quad = lane >> 4, l16 = lane & 15;
  int x7 = l16 & 7;

  // ---- staging: 32-bit byte offsets from uniform bases (buffers < 256MB) ----
  // chunk c: row = c>>3, kc = c&7, global slot = kc^(row&7) (rows 0,64,128,192
  // all = crow mod 8, so one sslot works for all four row groups)
  int crow = tid >> 3, kc = tid & 7;
  int sslot = kc ^ (crow & 7);
  const char* Ab = (const char*)A;
  const char* Bbb = (const char*)(B + (size_t)e * NLEN * KLEN);
  int a0r = rb + crow;       a0r = a0r > NSLOT - 1 ? NSLOT - 1 : a0r;
  int a1r = rb + 64 + crow;  a1r = a1r > NSLOT - 1 ? NSLOT - 1 : a1r;
  int a2r = rb + 128 + crow; a2r = a2r > NSLOT - 1 ? NSLOT - 1 : a2r;
  int a3r = rb + 192 + crow; a3r = a3r > NSLOT - 1 ? NSLOT - 1 : a3r;
  uint32_t aof0 = (uint32_t)a0r * (KLEN * 2) + sslot * 16;
  uint32_t aof1 = (uint32_t)a1r * (KLEN * 2) + sslot * 16;
  uint32_t aof2 = (uint32_t)a2r * (KLEN * 2) + sslot * 16;
  uint32_t aof3 = (uint32_t)a3r * (KLEN * 2) + sslot * 16;
  uint32_t bof0 = (uint32_t)(n0 + crow) * (KLEN * 2) + sslot * 16;
  uint32_t bof1 = bof0 + 64 * (KLEN * 2);
  uint32_t bof2 = bof0 + 128 * (KLEN * 2);
  uint32_t bof3 = bof0 + 192 * (KLEN * 2);
  const int d0 = tid * 8, d1 = (512 + tid) * 8, d2 = (1024 + tid) * 8, d3 = (1536 + tid) * 8;

#define STG_A0(p, kb) { async16(Ab + aof0 + (kb), &lA[p][d0]); async16(Ab + aof1 + (kb), &lA[p][d1]); }
#define STG_A1(p, kb) { async16(Ab + aof2 + (kb), &lA[p][d2]); async16(Ab + aof3 + (kb), &lA[p][d3]); }
#define STG_B0(p, kb) { async16(Bbb + bof0 + (kb), &lB[p][d0]); async16(Bbb + bof1 + (kb), &lB[p][d1]); }
#define STG_B1(p, kb) { async16(Bbb + bof2 + (kb), &lB[p][d2]); async16(Bbb + bof3 + (kb), &lB[p][d3]); }

  f32x4 acc[8][4];
#pragma unroll
  for (int i = 0; i < 8; ++i)
#pragma unroll
    for (int j = 0; j < 4; ++j) acc[i][j] = {0.f, 0.f, 0.f, 0.f};

  // ---- prologue: tile0 (4 halves) + tile1 A0,B0; wait tile0 only ----
  STG_A0(0, 0); STG_A1(0, 0); STG_B0(0, 0); STG_B1(0, 0);
  STG_A0(1, 128); STG_B0(1, 128);  // NT >= 16 always
  asm volatile("s_waitcnt vmcnt(4)" ::: "memory");
  __builtin_amdgcn_sched_barrier(0);
  __builtin_amdgcn_s_barrier();

  const int abase = (wm * 128 + l16) * 64;  // + mt*1024
  const int bbase = (wn * 64 + l16) * 64;   // + nt*1024
  const int s0off = (quad ^ x7) * 8;        // ks0 slot (swizzled)
  const int s1off = ((4 + quad) ^ x7) * 8;  // ks1 slot

#pragma unroll 2
  for (int t = 0; t < NT; ++t) {
    const int p = t & 1;
    const unsigned short* pA = lA[p];
    const unsigned short* pB = lB[p];
    const int kb1 = t * 128 + 128;  // byte k-offset of tile t+1
    bf16x8 a0lo[4], a0hi[4], a1[8], b0[4], b1[4];
    // -------- P1: read ks0-lo; stage (t+1,A1); MFMA ks0 x mt0-3 --------
#pragma unroll
    for (int mt = 0; mt < 4; ++mt) a0lo[mt] = *(const bf16x8*)&pA[abase + mt * 1024 + s0off];
#pragma unroll
    for (int nt = 0; nt < 4; ++nt) b0[nt] = *(const bf16x8*)&pB[bbase + nt * 1024 + s0off];
    if (t + 1 < NT) STG_A1(p ^ 1, kb1);
    __builtin_amdgcn_s_barrier();
    asm volatile("s_waitcnt lgkmcnt(0)" ::: "memory");
    __builtin_amdgcn_sched_barrier(0);
    __builtin_amdgcn_s_setprio(1);
#pragma unroll
    for (int mt = 0; mt < 4; ++mt)
#pragma unroll
      for (int nt = 0; nt < 4; ++nt) acc[mt][nt] = MFMA16(a0lo[mt], b0[nt], acc[mt][nt]);
    __builtin_amdgcn_s_setprio(0);
    __builtin_amdgcn_s_barrier();
    // -------- P2: read ks0-hi + all ks1; stage (t+1,B1); MFMA ks0 x mt4-7 --
#pragma unroll
    for (int mt = 0; mt < 4; ++mt) a0hi[mt] = *(const bf16x8*)&pA[abase + (4 + mt) * 1024 + s0off];
#pragma unroll
    for (int mt = 0; mt < 8; ++mt) a1[mt] = *(const bf16x8*)&pA[abase + mt * 1024 + s1off];
#pragma unroll
    for (int nt = 0; nt < 4; ++nt) b1[nt] = *(const bf16x8*)&pB[bbase + nt * 1024 + s1off];
    if (t + 1 < NT) STG_B1(p ^ 1, kb1);
    __builtin_amdgcn_s_barrier();
    asm volatile("s_waitcnt lgkmcnt(0)" ::: "memory");  // ALL buf-p reads done
    __builtin_amdgcn_sched_barrier(0);
    __builtin_amdgcn_s_setprio(1);
#pragma unroll
    for (int mt = 0; mt < 4; ++mt)
#pragma unroll
      for (int nt = 0; nt < 4; ++nt) acc[4 + mt][nt] = MFMA16(a0hi[mt], b0[nt], acc[4 + mt][nt]);
    __builtin_amdgcn_s_setprio(0);
    __builtin_amdgcn_s_barrier();
    // -------- P3: stage (t+2,A0)->p (safe: buf-p reads drained); MFMA ks1 --
    if (t + 2 < NT) STG_A0(p, kb1 + 128);
    __builtin_amdgcn_s_barrier();
    __builtin_amdgcn_s_setprio(1);
#pragma unroll
    for (int mt = 0; mt < 4; ++mt)
#pragma unroll
      for (int nt = 0; nt < 4; ++nt) acc[mt][nt] = MFMA16(a1[mt], b1[nt], acc[mt][nt]);
    __builtin_amdgcn_s_setprio(0);
    __builtin_amdgcn_s_barrier();
    // -------- P4: stage (t+2,B0)->p; MFMA ks1 x mt4-7; counted vmcnt -------
    if (t + 2 < NT) STG_B0(p, kb1 + 128);
    __builtin_amdgcn_s_barrier();
    __builtin_amdgcn_s_setprio(1);
#pragma unroll
    for (int mt = 0; mt < 4; ++mt)
#pragma unroll
      for (int nt = 0; nt < 4; ++nt) acc[4 + mt][nt] = MFMA16(a1[4 + mt], b1[nt], acc[4 + mt][nt]);
    __builtin_amdgcn_s_setprio(0);
    if (t + 2 < NT) {
      asm volatile("s_waitcnt vmcnt(4)" ::: "memory");  // tile t+1 resident
    } else {
      asm volatile("s_waitcnt vmcnt(0)" ::: "memory");  // epilogue drain
    }
    __builtin_amdgcn_sched_barrier(0);
    __builtin_amdgcn_s_barrier();
  }
#undef STG_A0
#undef STG_A1
#undef STG_B0
#undef STG_B1

  // epilogue: C/D layout col = lane&15, row = quad*4 + reg (m89-verified)
#pragma unroll
  for (int mt = 0; mt < 8; ++mt) {
#pragma unroll
    for (int r = 0; r < 4; ++r) {
      int mrow = wm * 128 + mt * 16 + quad * 4 + r;
      if (m0 + mrow < me) {
#pragma unroll
        for (int nt = 0; nt < 4; ++nt) {
          int col = n0 + wn * 64 + nt * 16 + l16;
          float v = acc[mt][nt][r] + bias[e * NLEN + col];
          if (RELU) v = fmaxf(v, 0.f);
          C[(size_t)(rb + mrow) * NLEN + col] = f2bf(v);
        }
      }
    }
  }
}

// ---- fallback 128x128 GEMM (fp32 B, used only if workspace too small) ----
template <int KLEN, int NLEN, bool RELU>
__global__ __launch_bounds__(256, 4) void gemm_bt(
    const unsigned short* __restrict__ A, const void* __restrict__ Bptr,
    const float* __restrict__ bias, unsigned short* __restrict__ C,
    const int* __restrict__ cnt, const int* __restrict__ off_) {
  const int NB_N = NLEN / 128;
  int panel = blockIdx.z * 8 + blockIdx.x;
  int e = panel / NB_N;
  int n0 = (panel % NB_N) * 128;
  int me = cnt[e];
  int m0 = blockIdx.y * 128;
  if (m0 >= me) return;
  int rb = off_[e] + m0;

  __shared__ unsigned short lA[8192];
  __shared__ unsigned short lB[8192];

  int tid = threadIdx.x;
  int wave = tid >> 6, lane = tid & 63;
  int wm = (wave >> 1) * 64, wn = (wave & 1) * 64;
  int quad = lane >> 4, l16 = lane & 15;
  int x7 = l16 & 7;

  int arow[4], brow[4], akx[4], ldst[4];
#pragma unroll
  for (int i = 0; i < 4; ++i) {
    int c = i * 256 + tid;
    int row = c >> 3;
    akx[i] = (c & 7) ^ (row & 7);
    ldst[i] = c * 8;
    brow[i] = row;
    int grow = rb + row;
    arow[i] = (grow > NSLOT - 1) ? (NSLOT - 1) : grow;
  }

  f32x4 acc[4][4];
#pragma unroll
  for (int i = 0; i < 4; ++i)
#pragma unroll
    for (int j = 0; j < 4; ++j) acc[i][j] = {0.f, 0.f, 0.f, 0.f};

  const float* Bf = (const float*)Bptr + (size_t)e * NLEN * KLEN;

  for (int k0 = 0; k0 < KLEN; k0 += 64) {
#pragma unroll
    for (int i = 0; i < 4; ++i)
      async16(A + (size_t)arow[i] * KLEN + k0 + akx[i] * 8, &lA[ldst[i]]);
#pragma unroll
    for (int i = 0; i < 4; ++i) {
      const float* gp = Bf + (size_t)(n0 + brow[i]) * KLEN + k0 + akx[i] * 8;
      float4 v0 = *(const float4*)gp;
      float4 v1 = *(const float4*)(gp + 4);
      union { unsigned short u[8]; bf16x8 v; } pk;
      pk.u[0] = f2bf(v0.x); pk.u[1] = f2bf(v0.y); pk.u[2] = f2bf(v0.z); pk.u[3] = f2bf(v0.w);
      pk.u[4] = f2bf(v1.x); pk.u[5] = f2bf(v1.y); pk.u[6] = f2bf(v1.z); pk.u[7] = f2bf(v1.w);
      *(bf16x8*)(&lB[ldst[i]]) = pk.v;
    }
    __syncthreads();
#pragma unroll
    for (int s = 0; s < 2; ++s) {
      int qx = (s * 4 + quad) ^ x7;
      bf16x8 af[4], bfr[4];
#pragma unroll
      for (int mt = 0; mt < 4; ++mt)
        af[mt] = *(const bf16x8*)(&lA[(wm + mt * 16 + l16) * 64 + qx * 8]);
#pragma unroll
      for (int nt = 0; nt < 4; ++nt)
        bfr[nt] = *(const bf16x8*)(&lB[(wn + nt * 16 + l16) * 64 + qx * 8]);
#pragma unroll
      for (int mt = 0; mt < 4; ++mt)
#pragma unroll
        for (int nt = 0; nt < 4; ++nt)
          acc[mt][nt] = MFMA16(af[mt], bfr[nt], acc[mt][nt]);
    }
    __syncthreads();
  }
#pragma unroll
  for (int mt = 0; mt < 4; ++mt) {
#pragma unroll
    for (int r = 0; r < 4; ++r) {
      int mrow = wm + mt * 16 + quad * 4 + r;
      if (m0 + mrow < me) {
#pragma unroll
        for (int nt = 0; nt < 4; ++nt) {
          int col = n0 + wn + nt * 16 + l16;
          float v = acc[mt][nt][r] + bias[e * NLEN + col];
          if (RELU) v = fmaxf(v, 0.f);
          C[(size_t)(rb + mrow) * NLEN + col] = f2bf(v);
        }
      }
    }
  }
}

// ---------------- combine + residual + LayerNorm ----------------
__global__ void ln_kernel(const float* __restrict__ x, const unsigned short* __restrict__ y,
                          const int* __restrict__ slot_of, const float* __restrict__ score2,
                          const float* __restrict__ lnw, const float* __restrict__ lnb,
                          float* __restrict__ out) {
  __shared__ float red[8];
  int n = blockIdx.x, t = threadIdx.x;
  int wave = t >> 6, lane = t & 63;
  int s0 = slot_of[n * 2], s1 = slot_of[n * 2 + 1];
  float w0 = score2[n * 2], w1 = score2[n * 2 + 1];
  float4 xv = *(const float4*)(x + (size_t)n * DIM + t * 4);
  ushort4 y0 = *(const ushort4*)(y + (size_t)s0 * DIM + t * 4);
  ushort4 y1 = *(const ushort4*)(y + (size_t)s1 * DIM + t * 4);
  float r0 = xv.x + w0 * bf2f(y0.x) + w1 * bf2f(y1.x);
  float r1 = xv.y + w0 * bf2f(y0.y) + w1 * bf2f(y1.y);
  float r2 = xv.z + w0 * bf2f(y0.z) + w1 * bf2f(y1.z);
  float r3 = xv.w + w0 * bf2f(y0.w) + w1 * bf2f(y1.w);
  float sum = r0 + r1 + r2 + r3;
  float sq = r0 * r0 + r1 * r1 + r2 * r2 + r3 * r3;
#pragma unroll
  for (int off = 32; off > 0; off >>= 1) {
    sum += __shfl_xor(sum, off, 64);
    sq += __shfl_xor(sq, off, 64);
  }
  if (lane == 0) { red[wave] = sum; red[4 + wave] = sq; }
  __syncthreads();
  sum = red[0] + red[1] + red[2] + red[3];
  sq = red[4] + red[5] + red[6] + red[7];
  float mu = sum * (1.f / DIM);
  float var = sq * (1.f / DIM) - mu * mu;
  float rs = rsqrtf(var + 1e-5f);
  float4 wv = *(const float4*)(lnw + t * 4);
  float4 bv = *(const float4*)(lnb + t * 4);
  float4 o;
  o.x = (r0 - mu) * rs * wv.x + bv.x;
  o.y = (r1 - mu) * rs * wv.y + bv.y;
  o.z = (r2 - mu) * rs * wv.z + bv.z;
  o.w = (r3 - mu) * rs * wv.w + bv.w;
  *(float4*)(out + (size_t)n * DIM + t * 4) = o;
}

// ---------------- launch ----------------
extern "C" void kernel_launch(void* const* d_in, const int* in_sizes, int n_in,
                              void* d_out, int out_size, void* d_ws, size_t ws_size,
                              hipStream_t stream) {
  const float* x = (const float*)d_in[0];
  const float* gw = (const float*)d_in[1];
  const float* gb = (const float*)d_in[2];
  const float* w1 = (const float*)d_in[3];
  const float* b1 = (const float*)d_in[4];
  const float* w2 = (const float*)d_in[5];
  const float* b2 = (const float*)d_in[6];
  const float* lnw = (const float*)d_in[7];
  const float* lnb = (const float*)d_in[8];
  float* out = (float*)d_out;
  char* ws = (char*)d_ws;

  int* cnt = (int*)(ws + 0);
  int* off_ = (int*)(ws + 64);
  int* hist = (int*)(ws + 4096);             // 64*8 ints
  int* base = (int*)(ws + 4096 + 2048);      // 64*8 ints
  int* expert2 = (int*)(ws + 65536);         // 16384 ints
  float* score2 = (float*)(ws + 2 * 65536);  // 16384 floats
  int* slot_of = (int*)(ws + 3 * 65536);     // 16384 ints
  int* token_of = (int*)(ws + 4 * 65536);    // 16384 ints
  const size_t XG_OFF = 524288;                           // 16384x1024 bf16 = 32 MB
  const size_t H_OFF = XG_OFF + (size_t)NSLOT * DIM * 2;  // 16384x4096 bf16 = 128 MB
  const size_t Y_OFF = H_OFF + (size_t)NSLOT * HID * 2;   // 16384x1024 bf16 = 32 MB
  const size_t WB1_OFF = Y_OFF + (size_t)NSLOT * DIM * 2;         // 64 MB
  const size_t WB2_OFF = WB1_OFF + (size_t)NEXP * HID * DIM * 2;  // 64 MB
  const size_t WS_NEED = WB2_OFF + (size_t)NEXP * DIM * HID * 2;
  unsigned short* xg = (unsigned short*)(ws + XG_OFF);
  unsigned short* h = (unsigned short*)(ws + H_OFF);
  unsigned short* y = (unsigned short*)(ws + Y_OFF);
  unsigned short* wb1 = (unsigned short*)(ws + WB1_OFF);
  unsigned short* wb2 = (unsigned short*)(ws + WB2_OFF);
  bool cvt_ok = ws_size >= WS_NEED;

  gate_kernel<<<N_TOK / 4, 256, 0, stream>>>(x, gw, gb, expert2, score2);
  hist_kernel<<<NBLK, 256, 0, stream>>>(expert2, hist);
  scan_kernel<<<1, 64, 0, stream>>>(hist, cnt, off_, base);
  assign_kernel<<<NBLK, 256, 0, stream>>>(expert2, base, slot_of, token_of);
  gather_kernel<<<NSLOT, 256, 0, stream>>>(x, token_of, xg);
  if (cvt_ok) {
    const int n4 = NEXP * HID * DIM / 4;
    cvt_kernel<<<4096, 256, 0, stream>>>(w1, wb1, n4);
    cvt_kernel<<<4096, 256, 0, stream>>>(w2, wb2, n4);
    // grid: x=8 (XCD), y = NSLOT/256 m-blocks (ragged early-out), z = panels/8
    gemm256<DIM, HID, true>
        <<<dim3(8, 64, (NEXP * HID / 256) / 8), 512, 0, stream>>>(xg, wb1, b1, h, cnt, off_);
    gemm256<HID, DIM, false>
        <<<dim3(8, 64, (NEXP * DIM / 256) / 8), 512, 0, stream>>>(h, wb2, b2, y, cnt, off_);
  } else {
    gemm_bt<DIM, HID, true>
        <<<dim3(8, 128, (NEXP * HID / 128) / 8), 256, 0, stream>>>(xg, w1, b1, h, cnt, off_);
    gemm_bt<HID, DIM, false>
        <<<dim3(8, 128, (NEXP * DIM / 128) / 8), 256, 0, stream>>>(h, w2, b2, y, cnt, off_);
  }
  ln_kernel<<<N_TOK, 256, 0, stream>>>(x, y, slot_of, score2, lnw, lnb, out);
}

// Round 4
// 800.677 us; speedup vs baseline: 1.4662x; 1.4662x over previous
//
#include <hip/hip_runtime.h>
#include <hip/hip_bf16.h>
#include <stdint.h>

#define N_TOK 8192
#define DIM 1024
#define HID 4096
#define NEXP 8
#define NSLOT 16384  // N_TOK * top_k
#define NBLK 64      // NSLOT / 256

typedef __attribute__((ext_vector_type(8))) __bf16 bf16x8;
typedef __attribute__((ext_vector_type(4))) float f32x4;

__device__ __forceinline__ unsigned short f2bf(float f) {
  unsigned int u = __float_as_uint(f);
  u += 0x7fff + ((u >> 16) & 1);  // round-to-nearest-even
  return (unsigned short)(u >> 16);
}
__device__ __forceinline__ float bf2f(unsigned short s) {
  return __uint_as_float(((unsigned int)s) << 16);
}
__device__ __forceinline__ void async16(const void* g, void* l) {
  __builtin_amdgcn_global_load_lds((__attribute__((address_space(1))) void*)(g),
                                   (__attribute__((address_space(3))) void*)(l), 16, 0, 0);
}
#define MFMA16(a, b, c) __builtin_amdgcn_mfma_f32_16x16x32_bf16(a, b, c, 0, 0, 0)

// ---------------- fp32 -> bf16 weight conversion ----------------
__global__ void cvt_kernel(const float* __restrict__ src, unsigned short* __restrict__ dst,
                           int n4) {
  int i = blockIdx.x * 256 + threadIdx.x;
  int stride = gridDim.x * 256;
  for (; i < n4; i += stride) {
    float4 v = ((const float4*)src)[i];
    ushort4 o;
    o.x = f2bf(v.x); o.y = f2bf(v.y); o.z = f2bf(v.z); o.w = f2bf(v.w);
    ((ushort4*)dst)[i] = o;
  }
}

// ---------------- gating: 1 wave per token (no global atomics) ----------------
__global__ void gate_kernel(const float* __restrict__ x, const float* __restrict__ gw,
                            const float* __restrict__ gb, int* __restrict__ expert2,
                            float* __restrict__ score2) {
  int token = blockIdx.x * 4 + (threadIdx.x >> 6);
  int lane = threadIdx.x & 63;
  const float4* xr = (const float4*)(x + (size_t)token * DIM);
  float acc[NEXP];
#pragma unroll
  for (int e = 0; e < NEXP; ++e) acc[e] = 0.f;
#pragma unroll
  for (int it = 0; it < DIM / 4 / 64; ++it) {
    int d = it * 64 + lane;
    float4 xv = xr[d];
#pragma unroll
    for (int e = 0; e < NEXP; ++e) {
      float4 wv = ((const float4*)(gw + e * DIM))[d];
      acc[e] += xv.x * wv.x + xv.y * wv.y + xv.z * wv.z + xv.w * wv.w;
    }
  }
#pragma unroll
  for (int off = 32; off > 0; off >>= 1) {
#pragma unroll
    for (int e = 0; e < NEXP; ++e) acc[e] += __shfl_xor(acc[e], off, 64);
  }
  if (lane == 0) {
    float lg[NEXP], mx = -1e30f;
#pragma unroll
    for (int e = 0; e < NEXP; ++e) { lg[e] = acc[e] + gb[e]; mx = fmaxf(mx, lg[e]); }
    float p[NEXP], s = 0.f;
#pragma unroll
    for (int e = 0; e < NEXP; ++e) { p[e] = expf(lg[e] - mx); s += p[e]; }
    float inv = 1.f / s;
#pragma unroll
    for (int e = 0; e < NEXP; ++e) p[e] *= inv;
    int i0 = 0;
#pragma unroll
    for (int e = 1; e < NEXP; ++e) if (p[e] > p[i0]) i0 = e;
    int i1 = (i0 == 0) ? 1 : 0;
#pragma unroll
    for (int e = 0; e < NEXP; ++e) if (e != i0 && p[e] > p[i1]) i1 = e;
    float eb = expf(p[i1] - p[i0]);  // <= 1
    float dn = 1.f / (1.f + eb);
    expert2[token * 2] = i0;
    expert2[token * 2 + 1] = i1;
    score2[token * 2] = dn;
    score2[token * 2 + 1] = eb * dn;
  }
}

// ---------------- routing: hist -> scan -> assign (LDS atomics only) ----------
__global__ void hist_kernel(const int* __restrict__ expert2, int* __restrict__ hist) {
  __shared__ int lh[NEXP];
  int b = blockIdx.x, t = threadIdx.x;
  if (t < NEXP) lh[t] = 0;
  __syncthreads();
  atomicAdd(&lh[expert2[b * 256 + t]], 1);
  __syncthreads();
  if (t < NEXP) hist[b * NEXP + t] = lh[t];
}

__global__ void scan_kernel(const int* __restrict__ hist, int* __restrict__ cnt,
                            int* __restrict__ off_, int* __restrict__ base) {
  __shared__ int lh[NBLK * NEXP];
  __shared__ int ltot[NEXP];
  __shared__ int loff[NEXP];
  int t = threadIdx.x;  // 64 threads
#pragma unroll
  for (int e = 0; e < NEXP; ++e) lh[t * NEXP + e] = hist[t * NEXP + e];
  __syncthreads();
  if (t < NEXP) {
    int s = 0;
    for (int b = 0; b < NBLK; ++b) { int v = lh[b * NEXP + t]; lh[b * NEXP + t] = s; s += v; }
    ltot[t] = s;
  }
  __syncthreads();
  if (t == 0) {
    int s = 0;
#pragma unroll
    for (int e = 0; e < NEXP; ++e) { loff[e] = s; s += ltot[e]; }
  }
  __syncthreads();
  if (t < NEXP) { cnt[t] = ltot[t]; off_[t] = loff[t]; }
#pragma unroll
  for (int e = 0; e < NEXP; ++e) base[t * NEXP + e] = loff[e] + lh[t * NEXP + e];
}

__global__ void assign_kernel(const int* __restrict__ expert2, const int* __restrict__ base,
                              int* __restrict__ slot_of, int* __restrict__ token_of) {
  __shared__ int lh[NEXP];
  int b = blockIdx.x, t = threadIdx.x;
  if (t < NEXP) lh[t] = 0;
  __syncthreads();
  int i = b * 256 + t;
  int e = expert2[i];
  int r = atomicAdd(&lh[e], 1);
  int slot = base[b * NEXP + e] + r;
  slot_of[i] = slot;
  token_of[slot] = i >> 1;
}

__global__ void gather_kernel(const float* __restrict__ x, const int* __restrict__ token_of,
                              unsigned short* __restrict__ xg) {
  int slot = blockIdx.x;
  int t = threadIdx.x;
  int n = token_of[slot];
  float4 v = *(const float4*)(x + (size_t)n * DIM + t * 4);
  ushort4 o;
  o.x = f2bf(v.x); o.y = f2bf(v.y); o.z = f2bf(v.z); o.w = f2bf(v.w);
  *(ushort4*)(xg + (size_t)slot * DIM + t * 4) = o;
}

// ============ 256x128 ring-3 counted-vmcnt bf16 MFMA GEMM ============
// C[m][n] = sum_k A[m][k]*B[n][k] (+bias, opt relu), rows = expert slots.
// BM=256, BN=128, BK=64. 512 threads = 8 waves (4M x 2N), wave out 64x64,
// acc[4][4] = 64 AGPR (round-1-proven size; round-3's acc[8][4]=128 +
// hoisted frags spilled -> this round removes the pressure structurally).
// LDS ring of 3 stages, 48KB each (A 32KB + B 16KB) = 144KB. Ring-3 makes
// staging race-free WITHOUT hoisting reads: tile t reads buf t%3; staging
// for t+2 targets buf (t+2)%3 == (t-1)%3, whose readers drained at tile
// t-1's end (lgkm0 + barrier) before tile t began.
// Swizzle: round-1-verified chunk-XOR (slot = kc^(row&7)); pre-swizzled
// GLOBAL source + swizzled READ, linear gload_lds dest (rule #21).
// Schedule per tile t (2 phases, by kstep; frags consumed IN-phase):
//   Ph1: ds_read ks0 frags (8xb128, 32 VGPR transient) | stage 3/6 chunks
//        of tile t+2 | bar; lgkm(0); schedbar; prio1; 16 MFMA; prio0; bar
//   Ph2: ds_read ks1 frags | stage 3/6 | bar; lgkm(0); schedbar; prio1;
//        16 MFMA; prio0; vmcnt(6) [counted: leaves exactly t+2's 6 loads
//        in flight => tile t+1 resident; issue-to-wait >= 1 full tile
//        (~1300cyc) > 900cyc HBM latency]; schedbar; bar
// Prologue: stage tile0+tile1 (12 loads); vmcnt(6). Epilogue: t=NT-2 waits
// vmcnt(0) (loads long since issued); t=NT-1 skips (ledger verified).
template <int KLEN, int NLEN, bool RELU>
__global__ __launch_bounds__(512, 2) void gemm_r3(
    const unsigned short* __restrict__ A, const unsigned short* __restrict__ B,
    const float* __restrict__ bias, unsigned short* __restrict__ C,
    const int* __restrict__ cnt, const int* __restrict__ off_) {
  const int NB_N = NLEN / 128;
  const int NT = KLEN / 64;
  int panel = blockIdx.z * 8 + blockIdx.x;  // T1: panel pinned to XCD
  int e = panel / NB_N;
  int n0 = (panel % NB_N) * 128;
  int me = cnt[e];
  int m0 = blockIdx.y * 256;
  if (m0 >= me) return;
  int rb = off_[e] + m0;

  // A stages: shorts [0, 49152) at s*16384; B stages: [49152, 73728) at +s*8192
  __shared__ unsigned short lds_[73728];  // 144 KB

  int tid = threadIdx.x;
  int wave = tid >> 6, lane = tid & 63;
  int wm = wave >> 1, wn = wave & 1;  // 4 M-waves x 2 N-waves
  int quad = lane >> 4, l16 = lane & 15;
  int x7 = l16 & 7;

  // ---- staging source offsets (32-bit, buffers < 256MB) ----
  // chunk c = j*512+tid: row = j*64 + (tid>>3), kc = tid&7,
  // global slot = kc ^ (row&7)  (row&7 == (tid>>3)&7 for all j)
  int crow = tid >> 3, kc = tid & 7;
  int sslot = kc ^ (crow & 7);
  const char* Ab = (const char*)A;
  const char* Bb = (const char*)(B + (size_t)e * NLEN * KLEN);
  uint32_t aof[4], bof[2];
#pragma unroll
  for (int j = 0; j < 4; ++j) {
    int gr = rb + j * 64 + crow;
    gr = gr > NSLOT - 1 ? NSLOT - 1 : gr;  // clamp; rows >= me never stored
    aof[j] = (uint32_t)gr * (KLEN * 2) + sslot * 16;
  }
#pragma unroll
  for (int j = 0; j < 2; ++j)
    bof[j] = (uint32_t)(n0 + j * 64 + crow) * (KLEN * 2) + sslot * 16;

#define STG_A2(sbuf, kb, j0)                                                  \
  {                                                                           \
    async16(Ab + aof[j0] + (kb), &lds_[(sbuf) * 16384 + ((j0)*512 + tid) * 8]); \
    async16(Ab + aof[(j0) + 1] + (kb),                                        \
            &lds_[(sbuf) * 16384 + (((j0) + 1) * 512 + tid) * 8]);            \
  }
#define STG_B1(sbuf, kb, j)                                                   \
  async16(Bb + bof[j] + (kb), &lds_[49152 + (sbuf) * 8192 + ((j)*512 + tid) * 8]);

  f32x4 acc[4][4];
#pragma unroll
  for (int i = 0; i < 4; ++i)
#pragma unroll
    for (int j = 0; j < 4; ++j) acc[i][j] = {0.f, 0.f, 0.f, 0.f};

  // ---- prologue: tile0 -> buf0, tile1 -> buf1 (6 loads each) ----
  STG_A2(0, 0, 0); STG_A2(0, 0, 2); STG_B1(0, 0, 0); STG_B1(0, 0, 1);
  STG_A2(1, 128, 0); STG_A2(1, 128, 2); STG_B1(1, 128, 0); STG_B1(1, 128, 1);
  asm volatile("s_waitcnt vmcnt(6)" ::: "memory");  // tile0 resident
  __builtin_amdgcn_sched_barrier(0);
  __builtin_amdgcn_s_barrier();

  const int abase = (wm * 64 + l16) * 64;  // + mt*1024 (shorts)
  const int bbase = (wn * 64 + l16) * 64;  // + nt*1024
  const int q0s = (quad ^ x7) * 8;         // ks0 chunk slot (swizzled)
  const int q1s = ((4 + quad) ^ x7) * 8;   // ks1 chunk slot

  int cur = 0;
#pragma unroll 1
  for (int t = 0; t < NT; ++t) {
    const int stg = (cur >= 1) ? cur - 1 : 2;  // (t+2)%3 == (t-1)%3
    const unsigned short* pa = &lds_[cur * 16384];
    const unsigned short* pb = &lds_[49152 + cur * 8192];
    const uint32_t kb2 = (uint32_t)(t + 2) << 7;
    const bool pre = (t + 2 < NT);
    bf16x8 af[4], bfr[4];
    // ---------------- Ph1: kstep 0 ----------------
#pragma unroll
    for (int mt = 0; mt < 4; ++mt) af[mt] = *(const bf16x8*)&pa[abase + mt * 1024 + q0s];
#pragma unroll
    for (int nt = 0; nt < 4; ++nt) bfr[nt] = *(const bf16x8*)&pb[bbase + nt * 1024 + q0s];
    if (pre) { STG_A2(stg, kb2, 0); STG_B1(stg, kb2, 0); }
    __builtin_amdgcn_s_barrier();
    asm volatile("s_waitcnt lgkmcnt(0)" ::: "memory");
    __builtin_amdgcn_sched_barrier(0);
    __builtin_amdgcn_s_setprio(1);
#pragma unroll
    for (int mt = 0; mt < 4; ++mt)
#pragma unroll
      for (int nt = 0; nt < 4; ++nt) acc[mt][nt] = MFMA16(af[mt], bfr[nt], acc[mt][nt]);
    __builtin_amdgcn_s_setprio(0);
    __builtin_amdgcn_s_barrier();
    // ---------------- Ph2: kstep 1 ----------------
#pragma unroll
    for (int mt = 0; mt < 4; ++mt) af[mt] = *(const bf16x8*)&pa[abase + mt * 1024 + q1s];
#pragma unroll
    for (int nt = 0; nt < 4; ++nt) bfr[nt] = *(const bf16x8*)&pb[bbase + nt * 1024 + q1s];
    if (pre) { STG_A2(stg, kb2, 2); STG_B1(stg, kb2, 1); }
    __builtin_amdgcn_s_barrier();
    asm volatile("s_waitcnt lgkmcnt(0)" ::: "memory");
    __builtin_amdgcn_sched_barrier(0);
    __builtin_amdgcn_s_setprio(1);
#pragma unroll
    for (int mt = 0; mt < 4; ++mt)
#pragma unroll
      for (int nt = 0; nt < 4; ++nt) acc[mt][nt] = MFMA16(af[mt], bfr[nt], acc[mt][nt]);
    __builtin_amdgcn_s_setprio(0);
    // counted tile-boundary wait: tile t+1 must be resident for next iter
    if (t + 1 < NT) {
      if (pre) {
        asm volatile("s_waitcnt vmcnt(6)" ::: "memory");  // leave t+2's 6 in flight
      } else {
        asm volatile("s_waitcnt vmcnt(0)" ::: "memory");  // epilogue drain (cheap)
      }
    }
    __builtin_amdgcn_sched_barrier(0);
    __builtin_amdgcn_s_barrier();
    cur = (cur == 2) ? 0 : cur + 1;
  }
#undef STG_A2
#undef STG_B1

  // epilogue: C/D layout col = lane&15, row = quad*4 + reg (m89-verified)
#pragma unroll
  for (int mt = 0; mt < 4; ++mt) {
#pragma unroll
    for (int r = 0; r < 4; ++r) {
      int mrow = wm * 64 + mt * 16 + quad * 4 + r;
      if (m0 + mrow < me) {
#pragma unroll
        for (int nt = 0; nt < 4; ++nt) {
          int col = n0 + wn * 64 + nt * 16 + l16;
          float v = acc[mt][nt][r] + bias[e * NLEN + col];
          if (RELU) v = fmaxf(v, 0.f);
          C[(size_t)(rb + mrow) * NLEN + col] = f2bf(v);
        }
      }
    }
  }
}

// ---- fallback 128x128 GEMM (fp32 B, used only if workspace too small) ----
template <int KLEN, int NLEN, bool RELU>
__global__ __launch_bounds__(256, 4) void gemm_bt(
    const unsigned short* __restrict__ A, const void* __restrict__ Bptr,
    const float* __restrict__ bias, unsigned short* __restrict__ C,
    const int* __restrict__ cnt, const int* __restrict__ off_) {
  const int NB_N = NLEN / 128;
  int panel = blockIdx.z * 8 + blockIdx.x;
  int e = panel / NB_N;
  int n0 = (panel % NB_N) * 128;
  int me = cnt[e];
  int m0 = blockIdx.y * 128;
  if (m0 >= me) return;
  int rb = off_[e] + m0;

  __shared__ unsigned short lA[8192];
  __shared__ unsigned short lB[8192];

  int tid = threadIdx.x;
  int wave = tid >> 6, lane = tid & 63;
  int wm = (wave >> 1) * 64, wn = (wave & 1) * 64;
  int quad = lane >> 4, l16 = lane & 15;
  int x7 = l16 & 7;

  int arow[4], brow[4], akx[4], ldst[4];
#pragma unroll
  for (int i = 0; i < 4; ++i) {
    int c = i * 256 + tid;
    int row = c >> 3;
    akx[i] = (c & 7) ^ (row & 7);
    ldst[i] = c * 8;
    brow[i] = row;
    int grow = rb + row;
    arow[i] = (grow > NSLOT - 1) ? (NSLOT - 1) : grow;
  }

  f32x4 acc[4][4];
#pragma unroll
  for (int i = 0; i < 4; ++i)
#pragma unroll
    for (int j = 0; j < 4; ++j) acc[i][j] = {0.f, 0.f, 0.f, 0.f};

  const float* Bf = (const float*)Bptr + (size_t)e * NLEN * KLEN;

  for (int k0 = 0; k0 < KLEN; k0 += 64) {
#pragma unroll
    for (int i = 0; i < 4; ++i)
      async16(A + (size_t)arow[i] * KLEN + k0 + akx[i] * 8, &lA[ldst[i]]);
#pragma unroll
    for (int i = 0; i < 4; ++i) {
      const float* gp = Bf + (size_t)(n0 + brow[i]) * KLEN + k0 + akx[i] * 8;
      float4 v0 = *(const float4*)gp;
      float4 v1 = *(const float4*)(gp + 4);
      union { unsigned short u[8]; bf16x8 v; } pk;
      pk.u[0] = f2bf(v0.x); pk.u[1] = f2bf(v0.y); pk.u[2] = f2bf(v0.z); pk.u[3] = f2bf(v0.w);
      pk.u[4] = f2bf(v1.x); pk.u[5] = f2bf(v1.y); pk.u[6] = f2bf(v1.z); pk.u[7] = f2bf(v1.w);
      *(bf16x8*)(&lB[ldst[i]]) = pk.v;
    }
    __syncthreads();
#pragma unroll
    for (int s = 0; s < 2; ++s) {
      int qx = (s * 4 + quad) ^ x7;
      bf16x8 af[4], bfr[4];
#pragma unroll
      for (int mt = 0; mt < 4; ++mt)
        af[mt] = *(const bf16x8*)(&lA[(wm + mt * 16 + l16) * 64 + qx * 8]);
#pragma unroll
      for (int nt = 0; nt < 4; ++nt)
        bfr[nt] = *(const bf16x8*)(&lB[(wn + nt * 16 + l16) * 64 + qx * 8]);
#pragma unroll
      for (int mt = 0; mt < 4; ++mt)
#pragma unroll
        for (int nt = 0; nt < 4; ++nt)
          acc[mt][nt] = MFMA16(af[mt], bfr[nt], acc[mt][nt]);
    }
    __syncthreads();
  }
#pragma unroll
  for (int mt = 0; mt < 4; ++mt) {
#pragma unroll
    for (int r = 0; r < 4; ++r) {
      int mrow = wm + mt * 16 + quad * 4 + r;
      if (m0 + mrow < me) {
#pragma unroll
        for (int nt = 0; nt < 4; ++nt) {
          int col = n0 + wn + nt * 16 + l16;
          float v = acc[mt][nt][r] + bias[e * NLEN + col];
          if (RELU) v = fmaxf(v, 0.f);
          C[(size_t)(rb + mrow) * NLEN + col] = f2bf(v);
        }
      }
    }
  }
}

// ---------------- combine + residual + LayerNorm ----------------
__global__ void ln_kernel(const float* __restrict__ x, const unsigned short* __restrict__ y,
                          const int* __restrict__ slot_of, const float* __restrict__ score2,
                          const float* __restrict__ lnw, const float* __restrict__ lnb,
                          float* __restrict__ out) {
  __shared__ float red[8];
  int n = blockIdx.x, t = threadIdx.x;
  int wave = t >> 6, lane = t & 63;
  int s0 = slot_of[n * 2], s1 = slot_of[n * 2 + 1];
  float w0 = score2[n * 2], w1 = score2[n * 2 + 1];
  float4 xv = *(const float4*)(x + (size_t)n * DIM + t * 4);
  ushort4 y0 = *(const ushort4*)(y + (size_t)s0 * DIM + t * 4);
  ushort4 y1 = *(const ushort4*)(y + (size_t)s1 * DIM + t * 4);
  float r0 = xv.x + w0 * bf2f(y0.x) + w1 * bf2f(y1.x);
  float r1 = xv.y + w0 * bf2f(y0.y) + w1 * bf2f(y1.y);
  float r2 = xv.z + w0 * bf2f(y0.z) + w1 * bf2f(y1.z);
  float r3 = xv.w + w0 * bf2f(y0.w) + w1 * bf2f(y1.w);
  float sum = r0 + r1 + r2 + r3;
  float sq = r0 * r0 + r1 * r1 + r2 * r2 + r3 * r3;
#pragma unroll
  for (int off = 32; off > 0; off >>= 1) {
    sum += __shfl_xor(sum, off, 64);
    sq += __shfl_xor(sq, off, 64);
  }
  if (lane == 0) { red[wave] = sum; red[4 + wave] = sq; }
  __syncthreads();
  sum = red[0] + red[1] + red[2] + red[3];
  sq = red[4] + red[5] + red[6] + red[7];
  float mu = sum * (1.f / DIM);
  float var = sq * (1.f / DIM) - mu * mu;
  float rs = rsqrtf(var + 1e-5f);
  float4 wv = *(const float4*)(lnw + t * 4);
  float4 bv = *(const float4*)(lnb + t * 4);
  float4 o;
  o.x = (r0 - mu) * rs * wv.x + bv.x;
  o.y = (r1 - mu) * rs * wv.y + bv.y;
  o.z = (r2 - mu) * rs * wv.z + bv.z;
  o.w = (r3 - mu) * rs * wv.w + bv.w;
  *(float4*)(out + (size_t)n * DIM + t * 4) = o;
}

// ---------------- launch ----------------
extern "C" void kernel_launch(void* const* d_in, const int* in_sizes, int n_in,
                              void* d_out, int out_size, void* d_ws, size_t ws_size,
                              hipStream_t stream) {
  const float* x = (const float*)d_in[0];
  const float* gw = (const float*)d_in[1];
  const float* gb = (const float*)d_in[2];
  const float* w1 = (const float*)d_in[3];
  const float* b1 = (const float*)d_in[4];
  const float* w2 = (const float*)d_in[5];
  const float* b2 = (const float*)d_in[6];
  const float* lnw = (const float*)d_in[7];
  const float* lnb = (const float*)d_in[8];
  float* out = (float*)d_out;
  char* ws = (char*)d_ws;

  int* cnt = (int*)(ws + 0);
  int* off_ = (int*)(ws + 64);
  int* hist = (int*)(ws + 4096);             // 64*8 ints
  int* base = (int*)(ws + 4096 + 2048);      // 64*8 ints
  int* expert2 = (int*)(ws + 65536);         // 16384 ints
  float* score2 = (float*)(ws + 2 * 65536);  // 16384 floats
  int* slot_of = (int*)(ws + 3 * 65536);     // 16384 ints
  int* token_of = (int*)(ws + 4 * 65536);    // 16384 ints
  const size_t XG_OFF = 524288;                           // 16384x1024 bf16 = 32 MB
  const size_t H_OFF = XG_OFF + (size_t)NSLOT * DIM * 2;  // 16384x4096 bf16 = 128 MB
  const size_t Y_OFF = H_OFF + (size_t)NSLOT * HID * 2;   // 16384x1024 bf16 = 32 MB
  const size_t WB1_OFF = Y_OFF + (size_t)NSLOT * DIM * 2;         // 64 MB
  const size_t WB2_OFF = WB1_OFF + (size_t)NEXP * HID * DIM * 2;  // 64 MB
  const size_t WS_NEED = WB2_OFF + (size_t)NEXP * DIM * HID * 2;
  unsigned short* xg = (unsigned short*)(ws + XG_OFF);
  unsigned short* h = (unsigned short*)(ws + H_OFF);
  unsigned short* y = (unsigned short*)(ws + Y_OFF);
  unsigned short* wb1 = (unsigned short*)(ws + WB1_OFF);
  unsigned short* wb2 = (unsigned short*)(ws + WB2_OFF);
  bool cvt_ok = ws_size >= WS_NEED;

  gate_kernel<<<N_TOK / 4, 256, 0, stream>>>(x, gw, gb, expert2, score2);
  hist_kernel<<<NBLK, 256, 0, stream>>>(expert2, hist);
  scan_kernel<<<1, 64, 0, stream>>>(hist, cnt, off_, base);
  assign_kernel<<<NBLK, 256, 0, stream>>>(expert2, base, slot_of, token_of);
  gather_kernel<<<NSLOT, 256, 0, stream>>>(x, token_of, xg);
  if (cvt_ok) {
    const int n4 = NEXP * HID * DIM / 4;
    cvt_kernel<<<4096, 256, 0, stream>>>(w1, wb1, n4);
    cvt_kernel<<<4096, 256, 0, stream>>>(w2, wb2, n4);
    // grid: x=8 (XCD), y = NSLOT/256 m-blocks (ragged early-out), z = panels/8
    gemm_r3<DIM, HID, true>
        <<<dim3(8, 64, (NEXP * HID / 128) / 8), 512, 0, stream>>>(xg, wb1, b1, h, cnt, off_);
    gemm_r3<HID, DIM, false>
        <<<dim3(8, 64, (NEXP * DIM / 128) / 8), 512, 0, stream>>>(h, wb2, b2, y, cnt, off_);
  } else {
    gemm_bt<DIM, HID, true>
        <<<dim3(8, 128, (NEXP * HID / 128) / 8), 256, 0, stream>>>(xg, w1, b1, h, cnt, off_);
    gemm_bt<HID, DIM, false>
        <<<dim3(8, 128, (NEXP * DIM / 128) / 8), 256, 0, stream>>>(h, w2, b2, y, cnt, off_);
  }
  ln_kernel<<<N_TOK, 256, 0, stream>>>(x, y, slot_of, score2, lnw, lnb, out);
}

// Round 5
// 786.513 us; speedup vs baseline: 1.4926x; 1.0180x over previous
//
#include <hip/hip_runtime.h>
#include <hip/hip_bf16.h>
#include <stdint.h>

#define N_TOK 8192
#define DIM 1024
#define HID 4096
#define NEXP 8
#define NSLOT 16384  // N_TOK * top_k
#define NBLK 64      // NSLOT / 256

typedef __attribute__((ext_vector_type(8))) __bf16 bf16x8;
typedef __attribute__((ext_vector_type(4))) float f32x4;

__device__ __forceinline__ unsigned short f2bf(float f) {
  unsigned int u = __float_as_uint(f);
  u += 0x7fff + ((u >> 16) & 1);  // round-to-nearest-even
  return (unsigned short)(u >> 16);
}
__device__ __forceinline__ float bf2f(unsigned short s) {
  return __uint_as_float(((unsigned int)s) << 16);
}
__device__ __forceinline__ void async16(const void* g, void* l) {
  __builtin_amdgcn_global_load_lds((__attribute__((address_space(1))) void*)(g),
                                   (__attribute__((address_space(3))) void*)(l), 16, 0, 0);
}
#define MFMA16(a, b, c) __builtin_amdgcn_mfma_f32_16x16x32_bf16(a, b, c, 0, 0, 0)

// ---------------- fp32 -> bf16 weight conversion ----------------
__global__ void cvt_kernel(const float* __restrict__ src, unsigned short* __restrict__ dst,
                           int n4) {
  int i = blockIdx.x * 256 + threadIdx.x;
  int stride = gridDim.x * 256;
  for (; i < n4; i += stride) {
    float4 v = ((const float4*)src)[i];
    ushort4 o;
    o.x = f2bf(v.x); o.y = f2bf(v.y); o.z = f2bf(v.z); o.w = f2bf(v.w);
    ((ushort4*)dst)[i] = o;
  }
}

// ---------------- gating: 1 wave per token (no global atomics) ----------------
__global__ void gate_kernel(const float* __restrict__ x, const float* __restrict__ gw,
                            const float* __restrict__ gb, int* __restrict__ expert2,
                            float* __restrict__ score2) {
  int token = blockIdx.x * 4 + (threadIdx.x >> 6);
  int lane = threadIdx.x & 63;
  const float4* xr = (const float4*)(x + (size_t)token * DIM);
  float acc[NEXP];
#pragma unroll
  for (int e = 0; e < NEXP; ++e) acc[e] = 0.f;
#pragma unroll
  for (int it = 0; it < DIM / 4 / 64; ++it) {
    int d = it * 64 + lane;
    float4 xv = xr[d];
#pragma unroll
    for (int e = 0; e < NEXP; ++e) {
      float4 wv = ((const float4*)(gw + e * DIM))[d];
      acc[e] += xv.x * wv.x + xv.y * wv.y + xv.z * wv.z + xv.w * wv.w;
    }
  }
#pragma unroll
  for (int off = 32; off > 0; off >>= 1) {
#pragma unroll
    for (int e = 0; e < NEXP; ++e) acc[e] += __shfl_xor(acc[e], off, 64);
  }
  if (lane == 0) {
    float lg[NEXP], mx = -1e30f;
#pragma unroll
    for (int e = 0; e < NEXP; ++e) { lg[e] = acc[e] + gb[e]; mx = fmaxf(mx, lg[e]); }
    float p[NEXP], s = 0.f;
#pragma unroll
    for (int e = 0; e < NEXP; ++e) { p[e] = expf(lg[e] - mx); s += p[e]; }
    float inv = 1.f / s;
#pragma unroll
    for (int e = 0; e < NEXP; ++e) p[e] *= inv;
    int i0 = 0;
#pragma unroll
    for (int e = 1; e < NEXP; ++e) if (p[e] > p[i0]) i0 = e;
    int i1 = (i0 == 0) ? 1 : 0;
#pragma unroll
    for (int e = 0; e < NEXP; ++e) if (e != i0 && p[e] > p[i1]) i1 = e;
    float eb = expf(p[i1] - p[i0]);  // <= 1
    float dn = 1.f / (1.f + eb);
    expert2[token * 2] = i0;
    expert2[token * 2 + 1] = i1;
    score2[token * 2] = dn;
    score2[token * 2 + 1] = eb * dn;
  }
}

// ---------------- routing: hist -> scan -> assign (LDS atomics only) ----------
__global__ void hist_kernel(const int* __restrict__ expert2, int* __restrict__ hist) {
  __shared__ int lh[NEXP];
  int b = blockIdx.x, t = threadIdx.x;
  if (t < NEXP) lh[t] = 0;
  __syncthreads();
  atomicAdd(&lh[expert2[b * 256 + t]], 1);
  __syncthreads();
  if (t < NEXP) hist[b * NEXP + t] = lh[t];
}

__global__ void scan_kernel(const int* __restrict__ hist, int* __restrict__ cnt,
                            int* __restrict__ off_, int* __restrict__ base) {
  __shared__ int lh[NBLK * NEXP];
  __shared__ int ltot[NEXP];
  __shared__ int loff[NEXP];
  int t = threadIdx.x;  // 64 threads
#pragma unroll
  for (int e = 0; e < NEXP; ++e) lh[t * NEXP + e] = hist[t * NEXP + e];
  __syncthreads();
  if (t < NEXP) {
    int s = 0;
    for (int b = 0; b < NBLK; ++b) { int v = lh[b * NEXP + t]; lh[b * NEXP + t] = s; s += v; }
    ltot[t] = s;
  }
  __syncthreads();
  if (t == 0) {
    int s = 0;
#pragma unroll
    for (int e = 0; e < NEXP; ++e) { loff[e] = s; s += ltot[e]; }
  }
  __syncthreads();
  if (t < NEXP) { cnt[t] = ltot[t]; off_[t] = loff[t]; }
#pragma unroll
  for (int e = 0; e < NEXP; ++e) base[t * NEXP + e] = loff[e] + lh[t * NEXP + e];
}

__global__ void assign_kernel(const int* __restrict__ expert2, const int* __restrict__ base,
                              int* __restrict__ slot_of, int* __restrict__ token_of) {
  __shared__ int lh[NEXP];
  int b = blockIdx.x, t = threadIdx.x;
  if (t < NEXP) lh[t] = 0;
  __syncthreads();
  int i = b * 256 + t;
  int e = expert2[i];
  int r = atomicAdd(&lh[e], 1);
  int slot = base[b * NEXP + e] + r;
  slot_of[i] = slot;
  token_of[slot] = i >> 1;
}

__global__ void gather_kernel(const float* __restrict__ x, const int* __restrict__ token_of,
                              unsigned short* __restrict__ xg) {
  int slot = blockIdx.x;
  int t = threadIdx.x;
  int n = token_of[slot];
  float4 v = *(const float4*)(x + (size_t)n * DIM + t * 4);
  ushort4 o;
  o.x = f2bf(v.x); o.y = f2bf(v.y); o.z = f2bf(v.z); o.w = f2bf(v.w);
  *(ushort4*)(xg + (size_t)slot * DIM + t * 4) = o;
}

// ============ 256x128 ring-3 single-barrier bf16 MFMA GEMM ============
// C[m][n] = sum_k A[m][k]*B[n][k] (+bias, opt relu), rows = expert slots.
// BM=256, BN=128, BK=64. 512 threads = 8 waves (4M x 2N), wave out 64x64,
// acc[4][4] = 64 AGPR. LDS ring of 3 stages, 48KB each = 144KB.
// Round-5 change (round-4 post-mortem: 25% MfmaUtil == MFMA/(MFMA+LDS+
// 5 barriers) serial ratio; lockstep phase barriers serialized LDS-read
// time with MFMA time): ONE barrier per K-tile, counted per-wave lgkmcnt
// instead of lockstep drains. Ring-3 makes this race-free: tile t reads
// buf t%3; staging t+2 targets buf (t+2)%3 == (t-1)%3, whose readers all
// drained before tile (t-1)'s closing barrier. Within a tile waves drift,
// so one wave's MFMA overlaps other waves' ds_read drain -> per-CU time
// max(LDS,MFMA) not sum.
// Tile body: issue all 16 ds_reads (ks0+ks1) + 6 stage issues; lgkm(8)
// [ks0 landed, ks1 still in flight under ks0's MFMAs]; 16 MFMA; lgkm(0);
// 16 MFMA; vmcnt(6) [counted: leaves t+2's 6 loads in flight => t+1
// resident; issue-to-wait >= 1 full tile > 900cyc HBM latency]; barrier.
// Rule-18 sched_barrier(0) after every counted wait.
// Swizzle: round-1-verified chunk-XOR (slot = kc^(row&7)); pre-swizzled
// GLOBAL source + swizzled READ, linear gload_lds dest (rule #21).
template <int KLEN, int NLEN, bool RELU>
__global__ __launch_bounds__(512, 2) void gemm_r3(
    const unsigned short* __restrict__ A, const unsigned short* __restrict__ B,
    const float* __restrict__ bias, unsigned short* __restrict__ C,
    const int* __restrict__ cnt, const int* __restrict__ off_) {
  const int NB_N = NLEN / 128;
  const int NT = KLEN / 64;
  int panel = blockIdx.z * 8 + blockIdx.x;  // T1: panel pinned to XCD
  int e = panel / NB_N;
  int n0 = (panel % NB_N) * 128;
  int me = cnt[e];
  int m0 = blockIdx.y * 256;
  if (m0 >= me) return;
  int rb = off_[e] + m0;

  // A stages: shorts [0, 49152) at s*16384; B stages: [49152, 73728) at +s*8192
  __shared__ unsigned short lds_[73728];  // 144 KB

  int tid = threadIdx.x;
  int wave = tid >> 6, lane = tid & 63;
  int wm = wave >> 1, wn = wave & 1;  // 4 M-waves x 2 N-waves
  int quad = lane >> 4, l16 = lane & 15;
  int x7 = l16 & 7;

  // ---- staging source offsets (32-bit, buffers < 256MB) ----
  int crow = tid >> 3, kc = tid & 7;
  int sslot = kc ^ (crow & 7);
  const char* Ab = (const char*)A;
  const char* Bb = (const char*)(B + (size_t)e * NLEN * KLEN);
  uint32_t aof[4], bof[2];
#pragma unroll
  for (int j = 0; j < 4; ++j) {
    int gr = rb + j * 64 + crow;
    gr = gr > NSLOT - 1 ? NSLOT - 1 : gr;  // clamp; rows >= me never stored
    aof[j] = (uint32_t)gr * (KLEN * 2) + sslot * 16;
  }
#pragma unroll
  for (int j = 0; j < 2; ++j)
    bof[j] = (uint32_t)(n0 + j * 64 + crow) * (KLEN * 2) + sslot * 16;

#define STG_A2(sbuf, kb, j0)                                                  \
  {                                                                           \
    async16(Ab + aof[j0] + (kb), &lds_[(sbuf) * 16384 + ((j0)*512 + tid) * 8]); \
    async16(Ab + aof[(j0) + 1] + (kb),                                        \
            &lds_[(sbuf) * 16384 + (((j0) + 1) * 512 + tid) * 8]);            \
  }
#define STG_B1(sbuf, kb, j)                                                   \
  async16(Bb + bof[j] + (kb), &lds_[49152 + (sbuf) * 8192 + ((j)*512 + tid) * 8]);

  f32x4 acc[4][4];
#pragma unroll
  for (int i = 0; i < 4; ++i)
#pragma unroll
    for (int j = 0; j < 4; ++j) acc[i][j] = {0.f, 0.f, 0.f, 0.f};

  // ---- prologue: tile0 -> buf0, tile1 -> buf1 (6 loads each) ----
  STG_A2(0, 0, 0); STG_A2(0, 0, 2); STG_B1(0, 0, 0); STG_B1(0, 0, 1);
  STG_A2(1, 128, 0); STG_A2(1, 128, 2); STG_B1(1, 128, 0); STG_B1(1, 128, 1);
  asm volatile("s_waitcnt vmcnt(6)" ::: "memory");  // tile0 resident
  __builtin_amdgcn_sched_barrier(0);
  __builtin_amdgcn_s_barrier();

  const int abase = (wm * 64 + l16) * 64;  // + mt*1024 (shorts)
  const int bbase = (wn * 64 + l16) * 64;  // + nt*1024
  const int q0s = (quad ^ x7) * 8;         // ks0 chunk slot (swizzled)
  const int q1s = ((4 + quad) ^ x7) * 8;   // ks1 chunk slot

  int cur = 0;
#pragma unroll 1
  for (int t = 0; t < NT; ++t) {
    const int stg = (cur >= 1) ? cur - 1 : 2;  // (t+2)%3 == (t-1)%3
    const unsigned short* pa = &lds_[cur * 16384];
    const unsigned short* pb = &lds_[49152 + cur * 8192];
    const uint32_t kb2 = (uint32_t)(t + 2) << 7;
    const bool pre = (t + 2 < NT);
    bf16x8 a0[4], b0[4], a1[4], b1[4];
    // ---- issue ALL ds_reads (ks0 then ks1) + all 6 stage issues ----
#pragma unroll
    for (int mt = 0; mt < 4; ++mt) a0[mt] = *(const bf16x8*)&pa[abase + mt * 1024 + q0s];
#pragma unroll
    for (int nt = 0; nt < 4; ++nt) b0[nt] = *(const bf16x8*)&pb[bbase + nt * 1024 + q0s];
    if (pre) { STG_A2(stg, kb2, 0); STG_B1(stg, kb2, 0); }
#pragma unroll
    for (int mt = 0; mt < 4; ++mt) a1[mt] = *(const bf16x8*)&pa[abase + mt * 1024 + q1s];
#pragma unroll
    for (int nt = 0; nt < 4; ++nt) b1[nt] = *(const bf16x8*)&pb[bbase + nt * 1024 + q1s];
    if (pre) { STG_A2(stg, kb2, 2); STG_B1(stg, kb2, 1); }
    // ---- ks0 compute (ks1 reads still landing underneath) ----
    asm volatile("s_waitcnt lgkmcnt(8)" ::: "memory");
    __builtin_amdgcn_sched_barrier(0);
    __builtin_amdgcn_s_setprio(1);
#pragma unroll
    for (int mt = 0; mt < 4; ++mt)
#pragma unroll
      for (int nt = 0; nt < 4; ++nt) acc[mt][nt] = MFMA16(a0[mt], b0[nt], acc[mt][nt]);
    __builtin_amdgcn_s_setprio(0);
    // ---- ks1 compute ----
    asm volatile("s_waitcnt lgkmcnt(0)" ::: "memory");
    __builtin_amdgcn_sched_barrier(0);
    __builtin_amdgcn_s_setprio(1);
#pragma unroll
    for (int mt = 0; mt < 4; ++mt)
#pragma unroll
      for (int nt = 0; nt < 4; ++nt) acc[mt][nt] = MFMA16(a1[mt], b1[nt], acc[mt][nt]);
    __builtin_amdgcn_s_setprio(0);
    // ---- single tile-boundary sync: t+1 resident for ALL waves ----
    if (t + 1 < NT) {
      if (pre) {
        asm volatile("s_waitcnt vmcnt(6)" ::: "memory");  // leave t+2's 6 in flight
      } else {
        asm volatile("s_waitcnt vmcnt(0)" ::: "memory");  // epilogue drain (loads old)
      }
    }
    __builtin_amdgcn_sched_barrier(0);
    __builtin_amdgcn_s_barrier();
    cur = (cur == 2) ? 0 : cur + 1;
  }
#undef STG_A2
#undef STG_B1

  // epilogue: C/D layout col = lane&15, row = quad*4 + reg (m89-verified)
#pragma unroll
  for (int mt = 0; mt < 4; ++mt) {
#pragma unroll
    for (int r = 0; r < 4; ++r) {
      int mrow = wm * 64 + mt * 16 + quad * 4 + r;
      if (m0 + mrow < me) {
#pragma unroll
        for (int nt = 0; nt < 4; ++nt) {
          int col = n0 + wn * 64 + nt * 16 + l16;
          float v = acc[mt][nt][r] + bias[e * NLEN + col];
          if (RELU) v = fmaxf(v, 0.f);
          C[(size_t)(rb + mrow) * NLEN + col] = f2bf(v);
        }
      }
    }
  }
}

// ---- fallback 128x128 GEMM (fp32 B, used only if workspace too small) ----
template <int KLEN, int NLEN, bool RELU>
__global__ __launch_bounds__(256, 4) void gemm_bt(
    const unsigned short* __restrict__ A, const void* __restrict__ Bptr,
    const float* __restrict__ bias, unsigned short* __restrict__ C,
    const int* __restrict__ cnt, const int* __restrict__ off_) {
  const int NB_N = NLEN / 128;
  int panel = blockIdx.z * 8 + blockIdx.x;
  int e = panel / NB_N;
  int n0 = (panel % NB_N) * 128;
  int me = cnt[e];
  int m0 = blockIdx.y * 128;
  if (m0 >= me) return;
  int rb = off_[e] + m0;

  __shared__ unsigned short lA[8192];
  __shared__ unsigned short lB[8192];

  int tid = threadIdx.x;
  int wave = tid >> 6, lane = tid & 63;
  int wm = (wave >> 1) * 64, wn = (wave & 1) * 64;
  int quad = lane >> 4, l16 = lane & 15;
  int x7 = l16 & 7;

  int arow[4], brow[4], akx[4], ldst[4];
#pragma unroll
  for (int i = 0; i < 4; ++i) {
    int c = i * 256 + tid;
    int row = c >> 3;
    akx[i] = (c & 7) ^ (row & 7);
    ldst[i] = c * 8;
    brow[i] = row;
    int grow = rb + row;
    arow[i] = (grow > NSLOT - 1) ? (NSLOT - 1) : grow;
  }

  f32x4 acc[4][4];
#pragma unroll
  for (int i = 0; i < 4; ++i)
#pragma unroll
    for (int j = 0; j < 4; ++j) acc[i][j] = {0.f, 0.f, 0.f, 0.f};

  const float* Bf = (const float*)Bptr + (size_t)e * NLEN * KLEN;

  for (int k0 = 0; k0 < KLEN; k0 += 64) {
#pragma unroll
    for (int i = 0; i < 4; ++i)
      async16(A + (size_t)arow[i] * KLEN + k0 + akx[i] * 8, &lA[ldst[i]]);
#pragma unroll
    for (int i = 0; i < 4; ++i) {
      const float* gp = Bf + (size_t)(n0 + brow[i]) * KLEN + k0 + akx[i] * 8;
      float4 v0 = *(const float4*)gp;
      float4 v1 = *(const float4*)(gp + 4);
      union { unsigned short u[8]; bf16x8 v; } pk;
      pk.u[0] = f2bf(v0.x); pk.u[1] = f2bf(v0.y); pk.u[2] = f2bf(v0.z); pk.u[3] = f2bf(v0.w);
      pk.u[4] = f2bf(v1.x); pk.u[5] = f2bf(v1.y); pk.u[6] = f2bf(v1.z); pk.u[7] = f2bf(v1.w);
      *(bf16x8*)(&lB[ldst[i]]) = pk.v;
    }
    __syncthreads();
#pragma unroll
    for (int s = 0; s < 2; ++s) {
      int qx = (s * 4 + quad) ^ x7;
      bf16x8 af[4], bfr[4];
#pragma unroll
      for (int mt = 0; mt < 4; ++mt)
        af[mt] = *(const bf16x8*)(&lA[(wm + mt * 16 + l16) * 64 + qx * 8]);
#pragma unroll
      for (int nt = 0; nt < 4; ++nt)
        bfr[nt] = *(const bf16x8*)(&lB[(wn + nt * 16 + l16) * 64 + qx * 8]);
#pragma unroll
      for (int mt = 0; mt < 4; ++mt)
#pragma unroll
        for (int nt = 0; nt < 4; ++nt)
          acc[mt][nt] = MFMA16(af[mt], bfr[nt], acc[mt][nt]);
    }
    __syncthreads();
  }
#pragma unroll
  for (int mt = 0; mt < 4; ++mt) {
#pragma unroll
    for (int r = 0; r < 4; ++r) {
      int mrow = wm + mt * 16 + quad * 4 + r;
      if (m0 + mrow < me) {
#pragma unroll
        for (int nt = 0; nt < 4; ++nt) {
          int col = n0 + wn + nt * 16 + l16;
          float v = acc[mt][nt][r] + bias[e * NLEN + col];
          if (RELU) v = fmaxf(v, 0.f);
          C[(size_t)(rb + mrow) * NLEN + col] = f2bf(v);
        }
      }
    }
  }
}

// ---------------- combine + residual + LayerNorm ----------------
__global__ void ln_kernel(const float* __restrict__ x, const unsigned short* __restrict__ y,
                          const int* __restrict__ slot_of, const float* __restrict__ score2,
                          const float* __restrict__ lnw, const float* __restrict__ lnb,
                          float* __restrict__ out) {
  __shared__ float red[8];
  int n = blockIdx.x, t = threadIdx.x;
  int wave = t >> 6, lane = t & 63;
  int s0 = slot_of[n * 2], s1 = slot_of[n * 2 + 1];
  float w0 = score2[n * 2], w1 = score2[n * 2 + 1];
  float4 xv = *(const float4*)(x + (size_t)n * DIM + t * 4);
  ushort4 y0 = *(const ushort4*)(y + (size_t)s0 * DIM + t * 4);
  ushort4 y1 = *(const ushort4*)(y + (size_t)s1 * DIM + t * 4);
  float r0 = xv.x + w0 * bf2f(y0.x) + w1 * bf2f(y1.x);
  float r1 = xv.y + w0 * bf2f(y0.y) + w1 * bf2f(y1.y);
  float r2 = xv.z + w0 * bf2f(y0.z) + w1 * bf2f(y1.z);
  float r3 = xv.w + w0 * bf2f(y0.w) + w1 * bf2f(y1.w);
  float sum = r0 + r1 + r2 + r3;
  float sq = r0 * r0 + r1 * r1 + r2 * r2 + r3 * r3;
#pragma unroll
  for (int off = 32; off > 0; off >>= 1) {
    sum += __shfl_xor(sum, off, 64);
    sq += __shfl_xor(sq, off, 64);
  }
  if (lane == 0) { red[wave] = sum; red[4 + wave] = sq; }
  __syncthreads();
  sum = red[0] + red[1] + red[2] + red[3];
  sq = red[4] + red[5] + red[6] + red[7];
  float mu = sum * (1.f / DIM);
  float var = sq * (1.f / DIM) - mu * mu;
  float rs = rsqrtf(var + 1e-5f);
  float4 wv = *(const float4*)(lnw + t * 4);
  float4 bv = *(const float4*)(lnb + t * 4);
  float4 o;
  o.x = (r0 - mu) * rs * wv.x + bv.x;
  o.y = (r1 - mu) * rs * wv.y + bv.y;
  o.z = (r2 - mu) * rs * wv.z + bv.z;
  o.w = (r3 - mu) * rs * wv.w + bv.w;
  *(float4*)(out + (size_t)n * DIM + t * 4) = o;
}

// ---------------- launch ----------------
extern "C" void kernel_launch(void* const* d_in, const int* in_sizes, int n_in,
                              void* d_out, int out_size, void* d_ws, size_t ws_size,
                              hipStream_t stream) {
  const float* x = (const float*)d_in[0];
  const float* gw = (const float*)d_in[1];
  const float* gb = (const float*)d_in[2];
  const float* w1 = (const float*)d_in[3];
  const float* b1 = (const float*)d_in[4];
  const float* w2 = (const float*)d_in[5];
  const float* b2 = (const float*)d_in[6];
  const float* lnw = (const float*)d_in[7];
  const float* lnb = (const float*)d_in[8];
  float* out = (float*)d_out;
  char* ws = (char*)d_ws;

  int* cnt = (int*)(ws + 0);
  int* off_ = (int*)(ws + 64);
  int* hist = (int*)(ws + 4096);             // 64*8 ints
  int* base = (int*)(ws + 4096 + 2048);      // 64*8 ints
  int* expert2 = (int*)(ws + 65536);         // 16384 ints
  float* score2 = (float*)(ws + 2 * 65536);  // 16384 floats
  int* slot_of = (int*)(ws + 3 * 65536);     // 16384 ints
  int* token_of = (int*)(ws + 4 * 65536);    // 16384 ints
  const size_t XG_OFF = 524288;                           // 16384x1024 bf16 = 32 MB
  const size_t H_OFF = XG_OFF + (size_t)NSLOT * DIM * 2;  // 16384x4096 bf16 = 128 MB
  const size_t Y_OFF = H_OFF + (size_t)NSLOT * HID * 2;   // 16384x1024 bf16 = 32 MB
  const size_t WB1_OFF = Y_OFF + (size_t)NSLOT * DIM * 2;         // 64 MB
  const size_t WB2_OFF = WB1_OFF + (size_t)NEXP * HID * DIM * 2;  // 64 MB
  const size_t WS_NEED = WB2_OFF + (size_t)NEXP * DIM * HID * 2;
  unsigned short* xg = (unsigned short*)(ws + XG_OFF);
  unsigned short* h = (unsigned short*)(ws + H_OFF);
  unsigned short* y = (unsigned short*)(ws + Y_OFF);
  unsigned short* wb1 = (unsigned short*)(ws + WB1_OFF);
  unsigned short* wb2 = (unsigned short*)(ws + WB2_OFF);
  bool cvt_ok = ws_size >= WS_NEED;

  gate_kernel<<<N_TOK / 4, 256, 0, stream>>>(x, gw, gb, expert2, score2);
  hist_kernel<<<NBLK, 256, 0, stream>>>(expert2, hist);
  scan_kernel<<<1, 64, 0, stream>>>(hist, cnt, off_, base);
  assign_kernel<<<NBLK, 256, 0, stream>>>(expert2, base, slot_of, token_of);
  gather_kernel<<<NSLOT, 256, 0, stream>>>(x, token_of, xg);
  if (cvt_ok) {
    const int n4 = NEXP * HID * DIM / 4;
    cvt_kernel<<<4096, 256, 0, stream>>>(w1, wb1, n4);
    cvt_kernel<<<4096, 256, 0, stream>>>(w2, wb2, n4);
    // grid: x=8 (XCD), y = NSLOT/256 m-blocks (ragged early-out), z = panels/8
    gemm_r3<DIM, HID, true>
        <<<dim3(8, 64, (NEXP * HID / 128) / 8), 512, 0, stream>>>(xg, wb1, b1, h, cnt, off_);
    gemm_r3<HID, DIM, false>
        <<<dim3(8, 64, (NEXP * DIM / 128) / 8), 512, 0, stream>>>(h, wb2, b2, y, cnt, off_);
  } else {
    gemm_bt<DIM, HID, true>
        <<<dim3(8, 128, (NEXP * HID / 128) / 8), 256, 0, stream>>>(xg, w1, b1, h, cnt, off_);
    gemm_bt<HID, DIM, false>
        <<<dim3(8, 128, (NEXP * DIM / 128) / 8), 256, 0, stream>>>(h, w2, b2, y, cnt, off_);
  }
  ln_kernel<<<N_TOK, 256, 0, stream>>>(x, y, slot_of, score2, lnw, lnb, out);
}